// Round 5
// baseline (372.137 us; speedup 1.0000x reference)
//
#include <hip/hip_runtime.h>
#include <hip/hip_bf16.h>
#include <math.h>

#define NBLK 16
#define KD 32
#define NDIM 512        // NBLK*KD
#define INDIM 64
#define DT_C 0.05f
#define TAU_EPS_C 1e-6f
#define MROWS 16        // batch rows per tile
#define WGSIZE 1024     // 16 waves; wave j owns block j

// Transposed-layout design (round 6, verified): netT = MFMA(A=W, B=yT).
// D-layout == B-layout in-lane under k-permutation pi(q*8+i)=q*4+(i&3)+((i&4)?16:0),
// applied to weight A-frags at setup. D -> next B is a pure in-lane pack.
// Round 7: tanh via exp2+rcp (5 inst); two batch tiles per wave (ILP).
// Round 8 (FAILED): launch_bounds(1024,8) clamp -> 32 arch VGPRs -> spills.
// Round 9: grid=512 no occupancy gain — regs pin 16 waves/CU. TLP dead.
// Round 10: prod/cons flag pipeline replaced per-step __syncthreads: 216->171us.
// Round 11 (FAILED): whole-step reorder (pv+AR+dec all live across phases)
// -> +16 VGPRs -> scratch spills (FETCH 91->482MB), 171->221us.
// Round 12: same latency-hiding theory, register-frugal: per-TILE stagger
// {issue pv_u read -> REC_u (register-only, hides ~120cyc LDS) -> FWD_u
// (consumes pv_u) -> proj_u -> update_u}. dec_u now lives only within one
// tile iteration (8 floats, was 16 across both) — peak pressure BELOW
// round 3. Protocol unchanged from round 11 (no consF; publish-then-flag;
// back-pressure prodF[j+1] >= g-1; wave 15 flag-only).

typedef __attribute__((ext_vector_type(8))) short bf16x8;         // MFMA A/B frag
typedef __attribute__((ext_vector_type(4))) float f32x4;          // MFMA C/D frag
typedef __attribute__((ext_vector_type(4))) unsigned int u32x4;   // 16B LDS slot

#define MFMA16(a,b,c) __builtin_amdgcn_mfma_f32_16x16x32_bf16((a),(b),(c),0,0,0)

// tanh = 1 - 2/(exp2(x*2log2e)+1): mul, exp, add, rcp, fma — no v_div_* sequence
__device__ __forceinline__ float fast_tanh(float x){
    float e = __builtin_amdgcn_exp2f(x * 2.885390081777927f);  // 2*log2(e)
    float r = __builtin_amdgcn_rcpf(e + 1.0f);
    return fmaf(-2.0f, r, 1.0f);
}
// cheap pack: round-half-away (<=0.5 ulp) + byte-perm
__device__ __forceinline__ unsigned int pack_bf2_fast(float a, float b){
    unsigned int ua = __float_as_uint(a) + 0x8000u;
    unsigned int ub = __float_as_uint(b) + 0x8000u;
    return __builtin_amdgcn_perm(ua, ub, 0x03020706);  // lo16=a.hi16, hi16=b.hi16
}
__device__ __forceinline__ unsigned short f2bf(float f){
    __hip_bfloat16 h = __float2bfloat16(f);   // RNE (setup only)
    return *reinterpret_cast<unsigned short*>(&h);
}

union FragU { bf16x8 h; u32x4 u; };

__device__ __forceinline__ bf16x8 pack8_fast(const float* a, const float* b){
    FragU z;
    z.u.x = pack_bf2_fast(a[0], a[1]);
    z.u.y = pack_bf2_fast(a[2], a[3]);
    z.u.z = pack_bf2_fast(b[0], b[1]);
    z.u.w = pack_bf2_fast(b[2], b[3]);
    return z.h;
}
__device__ __forceinline__ bf16x8 pack8_rne(f32x4 a, f32x4 b){
    bf16x8 r;
    r[0]=(short)f2bf(a[0]); r[1]=(short)f2bf(a[1]); r[2]=(short)f2bf(a[2]); r[3]=(short)f2bf(a[3]);
    r[4]=(short)f2bf(b[0]); r[5]=(short)f2bf(b[1]); r[6]=(short)f2bf(b[2]); r[7]=(short)f2bf(b[3]);
    return r;
}
// Weight A-frag under pi: two contiguous float4 loads per frag
__device__ __forceinline__ bf16x8 afrag_pi(const float* __restrict__ Wrow, int q){
    f32x4 lo = *(const f32x4*)(Wrow + q*4);
    f32x4 hi = *(const f32x4*)(Wrow + 16 + q*4);
    return pack8_rne(lo, hi);
}

__global__ __launch_bounds__(WGSIZE, 4)
void ltcn_kernel(const float* __restrict__ y_in,
                 const float* __restrict__ u_t,
                 const float* __restrict__ W_in,
                 const float* __restrict__ b_in,
                 const float* __restrict__ W_fwd,
                 const float* __restrict__ b_fwd,
                 const float* __restrict__ W_rec,
                 const float* __restrict__ b_rec,
                 const float* __restrict__ E_l,
                 const float* __restrict__ E_l_r,
                 const float* __restrict__ tau_raw,
                 const int* __restrict__ n_steps_p,
                 float* __restrict__ y_out,
                 int batch)
{
    // [slot=g&1][tile][wave*64+lane] 16B slots — 64 KB, stride-1 (conflict-free)
    __shared__ u32x4 Ylds[2][2][NBLK * 64];
    __shared__ int prodF[NBLK];   // last step published by wave j

    const int tid  = threadIdx.x;
    const int j    = tid >> 6;
    const int lane = tid & 63;
    const int q    = lane >> 4;
    const int b15  = lane & 15;
    const int ns   = n_steps_p[0];

    if (tid < NBLK) prodF[tid] = -1;
    __syncthreads();   // only barrier in the kernel (flag init)

    // ---- setup: pi-permuted weight A-frags + bias/invtau at D positions ----
    const float* Wr = W_rec + (size_t)j * KD * KD;
    const float* Wf = W_fwd + (size_t)((j > 0) ? (j-1) : 0) * KD * KD;
    const float* Ee = E_l   + (size_t)j * KD * KD;
    const float* Er = E_l_r + (size_t)j * KD * KD;

    bf16x8 Arec[2], Afwd[2], AEl[2], AElr[2];
    f32x4  cR[2], cF[2];
    float  itau[2][4];
    #pragma unroll
    for (int f = 0; f < 2; ++f){
        const int row = f*16 + b15;
        Arec[f] = afrag_pi(Wr + row*KD, q);
        Afwd[f] = afrag_pi(Wf + row*KD, q);
        AEl[f]  = afrag_pi(Ee + row*KD, q);
        AElr[f] = afrag_pi(Er + row*KD, q);
        #pragma unroll
        for (int r = 0; r < 4; ++r){
            const int lp = f*16 + q*4 + r;
            cR[f][r] = b_rec[j*KD + lp];
            cF[f][r] = (j > 0) ? b_fwd[(j-1)*KD + lp] : 0.f;
            float tr = tau_raw[j*KD + lp];
            float sp = fmaxf(tr, 0.f) + log1pf(__expf(-fabsf(tr)));
            itau[f][r] = 1.0f / (sp + TAU_EPS_C);
        }
    }
    const f32x4 zero = {0.f, 0.f, 0.f, 0.f};
    const int pairs = (batch / MROWS) / 2;

    int g = 0;   // global step counter — continuous across tile-pairs

    for (int p = blockIdx.x; p < pairs; p += gridDim.x){
        const int row0A = (2*p)     * MROWS;
        const int row0B = (2*p + 1) * MROWS;

        // ---- load y (fp32, D positions) for both tiles ----
        float yv[2][2][4];
        #pragma unroll
        for (int f = 0; f < 2; ++f){
            f32x4 ta = *(const f32x4*)&y_in[(size_t)(row0A + b15)*NDIM + j*KD + f*16 + q*4];
            f32x4 tb = *(const f32x4*)&y_in[(size_t)(row0B + b15)*NDIM + j*KD + f*16 + q*4];
            #pragma unroll
            for (int r = 0; r < 4; ++r){ yv[0][f][r] = ta[r]; yv[1][f][r] = tb[r]; }
        }

        // ---- wave 0: net0 via MFMA for both tiles (step-invariant) ----
        bf16x8 AO0[2] = {{0,0,0,0,0,0,0,0},{0,0,0,0,0,0,0,0}};
        if (j == 0){
            #pragma unroll
            for (int u = 0; u < 2; ++u){
                const int r0 = u ? row0B : row0A;
                f32x4 acc[2];
                #pragma unroll
                for (int f = 0; f < 2; ++f)
                #pragma unroll
                for (int r = 0; r < 4; ++r) acc[f][r] = b_in[f*16 + q*4 + r];
                #pragma unroll
                for (int c = 0; c < 2; ++c){
                    const float* up = &u_t[(size_t)(r0 + b15)*INDIM + c*32 + q*8];
                    bf16x8 uB = pack8_rne(*(const f32x4*)up, *(const f32x4*)(up + 4));
                    #pragma unroll
                    for (int f = 0; f < 2; ++f){
                        const float* wp = &W_in[(size_t)(f*16 + b15)*INDIM + c*32 + q*8];
                        bf16x8 wA = pack8_rne(*(const f32x4*)wp, *(const f32x4*)(wp + 4));
                        acc[f] = MFMA16(wA, uB, acc[f]);
                    }
                }
                float n0[2][4];
                #pragma unroll
                for (int f = 0; f < 2; ++f)
                #pragma unroll
                for (int r = 0; r < 4; ++r) n0[f][r] = fast_tanh(acc[f][r]);
                AO0[u] = pack8_fast(n0[0], n0[1]);
            }
        }

        for (int s = 0; s < ns; ++s){
            // pack own y slices (B-frags; also used locally for rec net)
            bf16x8 yB[2];
            #pragma unroll
            for (int u = 0; u < 2; ++u) yB[u] = pack8_fast(yv[u][0], yv[u][1]);

            // ---- back-pressure + publish (wave 15: flag only) ----
            if (j < NBLK-1){
                // slot g&1 holds step g-2; prodF[j+1]>=g-1 implies wave j+1
                // finished step g-2 entirely (incl. its reads of this slot)
                while (__hip_atomic_load(&prodF[j+1], __ATOMIC_ACQUIRE,
                                         __HIP_MEMORY_SCOPE_WORKGROUP) < g - 1)
                    __builtin_amdgcn_s_sleep(1);
                #pragma unroll
                for (int u = 0; u < 2; ++u){
                    FragU w; w.h = yB[u];
                    Ylds[g & 1][u][j*64 + lane] = w.u;
                }
            }
            if (lane == 0)
                __hip_atomic_store(&prodF[j], g, __ATOMIC_RELEASE,
                                   __HIP_MEMORY_SCOPE_WORKGROUP);

            // ---- consumer spin (once per step) ----
            if (j > 0){
                while (__hip_atomic_load(&prodF[j-1], __ATOMIC_ACQUIRE,
                                         __HIP_MEMORY_SCOPE_WORKGROUP) < g)
                    __builtin_amdgcn_s_sleep(1);
            }

            // ---- per-tile staggered pipeline: read -> REC -> FWD -> proj ----
            #pragma unroll
            for (int u = 0; u < 2; ++u){
                // issue pv read first; latency hides under REC (pv-independent)
                FragU pv;
                if (j > 0) pv.u = Ylds[g & 1][u][(j-1)*64 + lane];

                // REC phase (register-only inputs)
                f32x4 g0 = MFMA16(Arec[0], yB[u], cR[0]);
                f32x4 g1 = MFMA16(Arec[1], yB[u], cR[1]);
                float dec[2][4];
                float nr[2][4];
                #pragma unroll
                for (int r = 0; r < 4; ++r){
                    nr[0][r] = fast_tanh(g0[r]);
                    nr[1][r] = fast_tanh(g1[r]);
                    dec[0][r] = itau[0][r] + fabsf(nr[0][r]);
                    dec[1][r] = itau[1][r] + fabsf(nr[1][r]);
                }
                bf16x8 AR = pack8_fast(nr[0], nr[1]);

                // FWD phase (consumes pv; wave 0 uses step-invariant AO0)
                bf16x8 AO;
                if (j > 0){
                    f32x4 a0 = MFMA16(Afwd[0], pv.h, cF[0]);
                    f32x4 a1 = MFMA16(Afwd[1], pv.h, cF[1]);
                    float nf[2][4];
                    #pragma unroll
                    for (int r = 0; r < 4; ++r){
                        nf[0][r] = fast_tanh(a0[r]);
                        nf[1][r] = fast_tanh(a1[r]);
                        dec[0][r] += fabsf(nf[0][r]);
                        dec[1][r] += fabsf(nf[1][r]);
                    }
                    AO = pack8_fast(nf[0], nf[1]);
                } else {
                    AO = AO0[u];
                    FragU w; w.h = AO0[u];
                    unsigned int ws[4] = {w.u.x, w.u.y, w.u.z, w.u.w};
                    #pragma unroll
                    for (int f = 0; f < 2; ++f)
                    #pragma unroll
                    for (int r = 0; r < 4; ++r){
                        unsigned int word = ws[f*2 + (r >> 1)];
                        unsigned int bits = (r & 1) ? (word & 0xFFFF0000u) : (word << 16);
                        dec[f][r] += fabsf(__uint_as_float(bits));
                    }
                }

                // projections + update (dec consumed here — short live range)
                f32x4 o0 = MFMA16(AEl[0], AO, MFMA16(AElr[0], AR, zero));
                f32x4 o1 = MFMA16(AEl[1], AO, MFMA16(AElr[1], AR, zero));
                #pragma unroll
                for (int r = 0; r < 4; ++r){
                    yv[u][0][r] = fmaf(DT_C, fmaf(-yv[u][0][r], dec[0][r], o0[r]), yv[u][0][r]);
                    yv[u][1][r] = fmaf(DT_C, fmaf(-yv[u][1][r], dec[1][r], o1[r]), yv[u][1][r]);
                }
            }
            ++g;
        }

        // ---- store y for both tiles ----
        #pragma unroll
        for (int f = 0; f < 2; ++f){
            f32x4 sa = {yv[0][f][0], yv[0][f][1], yv[0][f][2], yv[0][f][3]};
            f32x4 sb = {yv[1][f][0], yv[1][f][1], yv[1][f][2], yv[1][f][3]};
            *(f32x4*)&y_out[(size_t)(row0A + b15)*NDIM + j*KD + f*16 + q*4] = sa;
            *(f32x4*)&y_out[(size_t)(row0B + b15)*NDIM + j*KD + f*16 + q*4] = sb;
        }
    }
}

extern "C" void kernel_launch(void* const* d_in, const int* in_sizes, int n_in,
                              void* d_out, int out_size, void* d_ws, size_t ws_size,
                              hipStream_t stream) {
    const float* y       = (const float*)d_in[0];
    const float* u_t     = (const float*)d_in[1];
    const float* W_in    = (const float*)d_in[2];
    const float* b_in    = (const float*)d_in[3];
    const float* W_fwd   = (const float*)d_in[4];
    const float* b_fwd   = (const float*)d_in[5];
    const float* W_rec   = (const float*)d_in[6];
    const float* b_rec   = (const float*)d_in[7];
    const float* E_l     = (const float*)d_in[8];
    const float* E_l_r   = (const float*)d_in[9];
    const float* tau_raw = (const float*)d_in[10];
    const int*   n_steps = (const int*)d_in[11];
    float* out = (float*)d_out;

    const int batch = in_sizes[0] / NDIM;
    // 1 WG/CU (register-pinned 16 waves/CU); 4 tile-pairs/WG.
    // grid=512 measured -5% (WG re-setup): keep 256.
    const int grid  = 256;

    hipLaunchKernelGGL(ltcn_kernel, dim3(grid), dim3(WGSIZE), 0, stream,
                       y, u_t, W_in, b_in, W_fwd, b_fwd, W_rec, b_rec,
                       E_l, E_l_r, tau_raw, n_steps, out, batch);
}

// Round 6
// 264.888 us; speedup vs baseline: 1.4049x; 1.4049x over previous
//
#include <hip/hip_runtime.h>
#include <hip/hip_bf16.h>
#include <math.h>

#define NBLK 16
#define KD 32
#define NDIM 512        // NBLK*KD
#define INDIM 64
#define DT_C 0.05f
#define TAU_EPS_C 1e-6f
#define MROWS 16        // batch rows per tile
#define WGSIZE 1024     // 16 waves; wave j owns block j
#define NSLOT 4         // LDS pipeline depth (round 13)

// Transposed-layout design (round 6, verified): netT = MFMA(A=W, B=yT).
// D-layout == B-layout in-lane under k-permutation pi(q*8+i)=q*4+(i&3)+((i&4)?16:0),
// applied to weight A-frags at setup. D -> next B is a pure in-lane pack.
// Round 7: tanh via exp2+rcp (5 inst); two batch tiles per wave (ILP).
// Round 8 (FAILED): launch_bounds(1024,8) clamp -> 32 arch VGPRs -> spills.
// Round 9: grid=512 no occupancy gain — regs pin 16 waves/CU. TLP dead.
// Round 10: prod/cons flag pipeline replaced per-step __syncthreads: 216->171us.
// Round 11 (FAILED): whole-step reorder -> +16 live VGPRs -> spills (FETCH
// 91->482MB), 221us. Round 12 (FAILED): per-tile stagger -> lost cross-tile
// ILP + residual spills, 280us. Champion = round-10 structure (171us,
// FETCH 91MB, VALUBusy 55). Reorders are refuted; phase order stays.
// Round 13: idle is 45% and CORRELATED (independent stalls would give
// 0.45^4~4% SIMD-idle). Channel = depth-2 back-pressure being marginal in
// steady state (skew~1) + s_sleep(1) 64-cyc spin quanta -> stall waves
// couple through the 16-stage chain. Fix: 4-slot ping-pong (128KB LDS,
// free at 1 WG/CU) gives slack 3 so producer spins never fire; pure poll
// (no s_sleep). Zero register-pressure change.

typedef __attribute__((ext_vector_type(8))) short bf16x8;         // MFMA A/B frag
typedef __attribute__((ext_vector_type(4))) float f32x4;          // MFMA C/D frag
typedef __attribute__((ext_vector_type(4))) unsigned int u32x4;   // 16B LDS slot

#define MFMA16(a,b,c) __builtin_amdgcn_mfma_f32_16x16x32_bf16((a),(b),(c),0,0,0)

// tanh = 1 - 2/(exp2(x*2log2e)+1): mul, exp, add, rcp, fma — no v_div_* sequence
__device__ __forceinline__ float fast_tanh(float x){
    float e = __builtin_amdgcn_exp2f(x * 2.885390081777927f);  // 2*log2(e)
    float r = __builtin_amdgcn_rcpf(e + 1.0f);
    return fmaf(-2.0f, r, 1.0f);
}
// cheap pack: round-half-away (<=0.5 ulp) + byte-perm
__device__ __forceinline__ unsigned int pack_bf2_fast(float a, float b){
    unsigned int ua = __float_as_uint(a) + 0x8000u;
    unsigned int ub = __float_as_uint(b) + 0x8000u;
    return __builtin_amdgcn_perm(ua, ub, 0x03020706);  // lo16=a.hi16, hi16=b.hi16
}
__device__ __forceinline__ unsigned short f2bf(float f){
    __hip_bfloat16 h = __float2bfloat16(f);   // RNE (setup only)
    return *reinterpret_cast<unsigned short*>(&h);
}

union FragU { bf16x8 h; u32x4 u; };

__device__ __forceinline__ bf16x8 pack8_fast(const float* a, const float* b){
    FragU z;
    z.u.x = pack_bf2_fast(a[0], a[1]);
    z.u.y = pack_bf2_fast(a[2], a[3]);
    z.u.z = pack_bf2_fast(b[0], b[1]);
    z.u.w = pack_bf2_fast(b[2], b[3]);
    return z.h;
}
__device__ __forceinline__ bf16x8 pack8_rne(f32x4 a, f32x4 b){
    bf16x8 r;
    r[0]=(short)f2bf(a[0]); r[1]=(short)f2bf(a[1]); r[2]=(short)f2bf(a[2]); r[3]=(short)f2bf(a[3]);
    r[4]=(short)f2bf(b[0]); r[5]=(short)f2bf(b[1]); r[6]=(short)f2bf(b[2]); r[7]=(short)f2bf(b[3]);
    return r;
}
// Weight A-frag under pi: two contiguous float4 loads per frag
__device__ __forceinline__ bf16x8 afrag_pi(const float* __restrict__ Wrow, int q){
    f32x4 lo = *(const f32x4*)(Wrow + q*4);
    f32x4 hi = *(const f32x4*)(Wrow + 16 + q*4);
    return pack8_rne(lo, hi);
}

__global__ __launch_bounds__(WGSIZE, 4)
void ltcn_kernel(const float* __restrict__ y_in,
                 const float* __restrict__ u_t,
                 const float* __restrict__ W_in,
                 const float* __restrict__ b_in,
                 const float* __restrict__ W_fwd,
                 const float* __restrict__ b_fwd,
                 const float* __restrict__ W_rec,
                 const float* __restrict__ b_rec,
                 const float* __restrict__ E_l,
                 const float* __restrict__ E_l_r,
                 const float* __restrict__ tau_raw,
                 const int* __restrict__ n_steps_p,
                 float* __restrict__ y_out,
                 int batch)
{
    // [slot=g&3][tile][wave*64+lane] 16B slots — 128 KB, stride-1 (conflict-free)
    __shared__ u32x4 Ylds[NSLOT][2][NBLK * 64];
    __shared__ int prodF[NBLK];   // last step published by wave j
    __shared__ int consF[NBLK];   // last step consumed (read) by wave j

    const int tid  = threadIdx.x;
    const int j    = tid >> 6;
    const int lane = tid & 63;
    const int q    = lane >> 4;
    const int b15  = lane & 15;
    const int ns   = n_steps_p[0];

    if (tid < NBLK){ prodF[tid] = -1; consF[tid] = -1; }
    __syncthreads();   // only barrier in the kernel (flag init)

    // ---- setup: pi-permuted weight A-frags + bias/invtau at D positions ----
    const float* Wr = W_rec + (size_t)j * KD * KD;
    const float* Wf = W_fwd + (size_t)((j > 0) ? (j-1) : 0) * KD * KD;
    const float* Ee = E_l   + (size_t)j * KD * KD;
    const float* Er = E_l_r + (size_t)j * KD * KD;

    bf16x8 Arec[2], Afwd[2], AEl[2], AElr[2];
    f32x4  cR[2], cF[2];
    float  itau[2][4];
    #pragma unroll
    for (int f = 0; f < 2; ++f){
        const int row = f*16 + b15;
        Arec[f] = afrag_pi(Wr + row*KD, q);
        Afwd[f] = afrag_pi(Wf + row*KD, q);
        AEl[f]  = afrag_pi(Ee + row*KD, q);
        AElr[f] = afrag_pi(Er + row*KD, q);
        #pragma unroll
        for (int r = 0; r < 4; ++r){
            const int lp = f*16 + q*4 + r;
            cR[f][r] = b_rec[j*KD + lp];
            cF[f][r] = (j > 0) ? b_fwd[(j-1)*KD + lp] : 0.f;
            float tr = tau_raw[j*KD + lp];
            float sp = fmaxf(tr, 0.f) + log1pf(__expf(-fabsf(tr)));
            itau[f][r] = 1.0f / (sp + TAU_EPS_C);
        }
    }
    const f32x4 zero = {0.f, 0.f, 0.f, 0.f};
    const int pairs = (batch / MROWS) / 2;

    int g = 0;   // global step counter — continuous across tile-pairs

    for (int p = blockIdx.x; p < pairs; p += gridDim.x){
        const int row0A = (2*p)     * MROWS;
        const int row0B = (2*p + 1) * MROWS;

        // ---- load y (fp32, D positions) for both tiles ----
        float yv[2][2][4];
        #pragma unroll
        for (int f = 0; f < 2; ++f){
            f32x4 ta = *(const f32x4*)&y_in[(size_t)(row0A + b15)*NDIM + j*KD + f*16 + q*4];
            f32x4 tb = *(const f32x4*)&y_in[(size_t)(row0B + b15)*NDIM + j*KD + f*16 + q*4];
            #pragma unroll
            for (int r = 0; r < 4; ++r){ yv[0][f][r] = ta[r]; yv[1][f][r] = tb[r]; }
        }

        // ---- wave 0: net0 via MFMA for both tiles (step-invariant) ----
        bf16x8 AO0[2] = {{0,0,0,0,0,0,0,0},{0,0,0,0,0,0,0,0}};
        if (j == 0){
            #pragma unroll
            for (int u = 0; u < 2; ++u){
                const int r0 = u ? row0B : row0A;
                f32x4 acc[2];
                #pragma unroll
                for (int f = 0; f < 2; ++f)
                #pragma unroll
                for (int r = 0; r < 4; ++r) acc[f][r] = b_in[f*16 + q*4 + r];
                #pragma unroll
                for (int c = 0; c < 2; ++c){
                    const float* up = &u_t[(size_t)(r0 + b15)*INDIM + c*32 + q*8];
                    bf16x8 uB = pack8_rne(*(const f32x4*)up, *(const f32x4*)(up + 4));
                    #pragma unroll
                    for (int f = 0; f < 2; ++f){
                        const float* wp = &W_in[(size_t)(f*16 + b15)*INDIM + c*32 + q*8];
                        bf16x8 wA = pack8_rne(*(const f32x4*)wp, *(const f32x4*)(wp + 4));
                        acc[f] = MFMA16(wA, uB, acc[f]);
                    }
                }
                float n0[2][4];
                #pragma unroll
                for (int f = 0; f < 2; ++f)
                #pragma unroll
                for (int r = 0; r < 4; ++r) n0[f][r] = fast_tanh(acc[f][r]);
                AO0[u] = pack8_fast(n0[0], n0[1]);
            }
        }

        for (int s = 0; s < ns; ++s){
            // pack own y slices (B-frags; also kept in regs for rec net)
            bf16x8 yB[2];
            #pragma unroll
            for (int u = 0; u < 2; ++u) yB[u] = pack8_fast(yv[u][0], yv[u][1]);

            // ---- publish to consumer (wave j+1); wave 15 has no consumer ----
            if (j < NBLK-1){
                // slot g&3 holds step g-4; consumer must have read it.
                // With slack 3 this spin should never fire in steady state.
                while (__hip_atomic_load(&consF[j+1], __ATOMIC_ACQUIRE,
                                         __HIP_MEMORY_SCOPE_WORKGROUP) < g - NSLOT) {}
                #pragma unroll
                for (int u = 0; u < 2; ++u){
                    FragU w; w.h = yB[u];
                    Ylds[g & (NSLOT-1)][u][j*64 + lane] = w.u;
                }
                if (lane == 0)
                    __hip_atomic_store(&prodF[j], g, __ATOMIC_RELEASE,
                                       __HIP_MEMORY_SCOPE_WORKGROUP);
            }

            // ---- fwd nets (need y_{j-1}); wave 0 uses step-invariant AO0 ----
            float dec[2][2][4];
            bf16x8 AO[2];
            if (j > 0){
                while (__hip_atomic_load(&prodF[j-1], __ATOMIC_ACQUIRE,
                                         __HIP_MEMORY_SCOPE_WORKGROUP) < g) {}
                #pragma unroll
                for (int u = 0; u < 2; ++u){
                    FragU pv; pv.u = Ylds[g & (NSLOT-1)][u][(j-1)*64 + lane];
                    f32x4 a0 = MFMA16(Afwd[0], pv.h, cF[0]);
                    f32x4 a1 = MFMA16(Afwd[1], pv.h, cF[1]);
                    float nf[2][4];
                    #pragma unroll
                    for (int r = 0; r < 4; ++r){
                        nf[0][r] = fast_tanh(a0[r]);
                        nf[1][r] = fast_tanh(a1[r]);
                        dec[u][0][r] = itau[0][r] + fabsf(nf[0][r]);
                        dec[u][1][r] = itau[1][r] + fabsf(nf[1][r]);
                    }
                    AO[u] = pack8_fast(nf[0], nf[1]);
                }
                // ds_reads retired (MFMA consumed them) -> slot free for producer
                if (lane == 0)
                    __hip_atomic_store(&consF[j], g, __ATOMIC_RELEASE,
                                       __HIP_MEMORY_SCOPE_WORKGROUP);
            } else {
                // recompute dec from packed AO0 (cheap; keeps 16 VGPRs free)
                #pragma unroll
                for (int u = 0; u < 2; ++u){
                    AO[u] = AO0[u];
                    FragU w; w.h = AO0[u];
                    unsigned int ws[4] = {w.u.x, w.u.y, w.u.z, w.u.w};
                    #pragma unroll
                    for (int f = 0; f < 2; ++f)
                    #pragma unroll
                    for (int r = 0; r < 4; ++r){
                        unsigned int word = ws[f*2 + (r >> 1)];
                        unsigned int bits = (r & 1) ? (word & 0xFFFF0000u) : (word << 16);
                        dec[u][f][r] = itau[f][r] + fabsf(__uint_as_float(bits));
                    }
                }
            }

            // ---- rec nets + block-diagonal projections + update ----
            #pragma unroll
            for (int u = 0; u < 2; ++u){
                f32x4 g0 = MFMA16(Arec[0], yB[u], cR[0]);
                f32x4 g1 = MFMA16(Arec[1], yB[u], cR[1]);
                float nr[2][4];
                #pragma unroll
                for (int r = 0; r < 4; ++r){
                    nr[0][r] = fast_tanh(g0[r]);
                    nr[1][r] = fast_tanh(g1[r]);
                    dec[u][0][r] += fabsf(nr[0][r]);
                    dec[u][1][r] += fabsf(nr[1][r]);
                }
                bf16x8 AR = pack8_fast(nr[0], nr[1]);

                f32x4 o0 = MFMA16(AEl[0], AO[u], MFMA16(AElr[0], AR, zero));
                f32x4 o1 = MFMA16(AEl[1], AO[u], MFMA16(AElr[1], AR, zero));
                #pragma unroll
                for (int r = 0; r < 4; ++r){
                    yv[u][0][r] = fmaf(DT_C, fmaf(-yv[u][0][r], dec[u][0][r], o0[r]), yv[u][0][r]);
                    yv[u][1][r] = fmaf(DT_C, fmaf(-yv[u][1][r], dec[u][1][r], o1[r]), yv[u][1][r]);
                }
            }
            ++g;
        }

        // ---- store y for both tiles ----
        #pragma unroll
        for (int f = 0; f < 2; ++f){
            f32x4 sa = {yv[0][f][0], yv[0][f][1], yv[0][f][2], yv[0][f][3]};
            f32x4 sb = {yv[1][f][0], yv[1][f][1], yv[1][f][2], yv[1][f][3]};
            *(f32x4*)&y_out[(size_t)(row0A + b15)*NDIM + j*KD + f*16 + q*4] = sa;
            *(f32x4*)&y_out[(size_t)(row0B + b15)*NDIM + j*KD + f*16 + q*4] = sb;
        }
    }
}

extern "C" void kernel_launch(void* const* d_in, const int* in_sizes, int n_in,
                              void* d_out, int out_size, void* d_ws, size_t ws_size,
                              hipStream_t stream) {
    const float* y       = (const float*)d_in[0];
    const float* u_t     = (const float*)d_in[1];
    const float* W_in    = (const float*)d_in[2];
    const float* b_in    = (const float*)d_in[3];
    const float* W_fwd   = (const float*)d_in[4];
    const float* b_fwd   = (const float*)d_in[5];
    const float* W_rec   = (const float*)d_in[6];
    const float* b_rec   = (const float*)d_in[7];
    const float* E_l     = (const float*)d_in[8];
    const float* E_l_r   = (const float*)d_in[9];
    const float* tau_raw = (const float*)d_in[10];
    const int*   n_steps = (const int*)d_in[11];
    float* out = (float*)d_out;

    const int batch = in_sizes[0] / NDIM;
    // 1 WG/CU (register-pinned 16 waves/CU); 4 tile-pairs/WG.
    // grid=512 measured -5% (WG re-setup): keep 256.
    const int grid  = 256;

    hipLaunchKernelGGL(ltcn_kernel, dim3(grid), dim3(WGSIZE), 0, stream,
                       y, u_t, W_in, b_in, W_fwd, b_fwd, W_rec, b_rec,
                       E_l, E_l_r, tau_raw, n_steps, out, batch);
}